// Round 8
// baseline (158.197 us; speedup 1.0000x reference)
//
#include <hip/hip_runtime.h>
#include <hip/hip_bf16.h>

// Problem constants: B=2, T=2048, C=1024, H=16, D=64
#define BSZ 2
#define SEQ 2048
#define CDIM 1024
#define NHEAD 16
#define HDIM 64
#define M_GEMM (BSZ * SEQ)      // 4096
#define N_GEMM (3 * CDIM)       // 3072
#define K_GEMM CDIM             // 1024
#define QK_PITCH (2 * CDIM)     // 2048: qk buffer row pitch (Q|K only)

typedef __attribute__((ext_vector_type(8))) short short8;   // 8 bf16 = 16B
typedef __attribute__((ext_vector_type(4))) short short4v;  // 8B
typedef __attribute__((ext_vector_type(4))) float f32x4;

__device__ __forceinline__ short bf16_rn(float f) {
    unsigned u = __builtin_bit_cast(unsigned, f);
    u += 0x7FFF + ((u >> 16) & 1);          // round-to-nearest-even
    return (short)(u >> 16);
}

// async 16B global -> LDS (wave-uniform LDS base; HW adds lane*16)
__device__ __forceinline__ void gl2lds16(const short* g, short* l) {
    __builtin_amdgcn_global_load_lds(
        (const __attribute__((address_space(1))) unsigned int*)g,
        (__attribute__((address_space(3))) unsigned int*)l, 16, 0, 0);
}

// bare counted waits (NO "memory" clobber: that forces a full vmcnt0/lgkmcnt0
// drain by SIInsertWaitcnts). Ordering pinned with sched_barrier(0) instead.
#define WAITV4() asm volatile("s_waitcnt vmcnt(4)")
#define WAITV0() asm volatile("s_waitcnt vmcnt(0)")
#define LGKM0()  asm volatile("s_waitcnt lgkmcnt(0)")
#define SCB()    __builtin_amdgcn_sched_barrier(0)
#define BARRIER() __builtin_amdgcn_s_barrier()

// ------------- Kernel 0: fused fp32->bf16 conversions ------------------------
// blocks [0, 2048): x -> xb (same layout). blocks [2048, 2816): W -> W^T tiles.
__global__ __launch_bounds__(256) void cvt_fused(const float* __restrict__ X,
                                                 const float* __restrict__ W,
                                                 short* __restrict__ Xb,
                                                 short* __restrict__ WT) {
    const int tid = threadIdx.x;
    if (blockIdx.x < 2048) {
        size_t idx = ((size_t)blockIdx.x * 256 + tid) * 8;
        float4 a = *(const float4*)&X[idx];
        float4 b = *(const float4*)&X[idx + 4];
        short8 o;
        o[0] = bf16_rn(a.x); o[1] = bf16_rn(a.y); o[2] = bf16_rn(a.z); o[3] = bf16_rn(a.w);
        o[4] = bf16_rn(b.x); o[5] = bf16_rn(b.y); o[6] = bf16_rn(b.z); o[7] = bf16_rn(b.w);
        *(short8*)&Xb[idx] = o;
        return;
    }
    __shared__ short T[64][72];
    const int bid = blockIdx.x - 2048;          // 0..767
    const int n0 = (bid % 48) * 64;
    const int k0 = (bid / 48) * 64;
#pragma unroll
    for (int pass = 0; pass < 4; ++pass) {
        int i = pass * 256 + tid;
        int kr = i >> 4;
        int n4 = i & 15;
        float4 v = *(const float4*)&W[(size_t)(k0 + kr) * N_GEMM + n0 + n4 * 4];
        T[n4 * 4 + 0][kr] = bf16_rn(v.x);
        T[n4 * 4 + 1][kr] = bf16_rn(v.y);
        T[n4 * 4 + 2][kr] = bf16_rn(v.z);
        T[n4 * 4 + 3][kr] = bf16_rn(v.w);
    }
    __syncthreads();
#pragma unroll
    for (int pass = 0; pass < 2; ++pass) {
        int o = pass * 256 + tid;
        int nr = o >> 3;
        int c8 = o & 7;
        *(short8*)&WT[(size_t)(n0 + nr) * K_GEMM + k0 + c8 * 8] =
            *(const short8*)&T[nr][c8 * 8];
    }
}

// -------- Kernel 1: qkv = x @ W + b — 256x256 tile, 8-wave, m201-style phases
// R19 winner: two barriers per phase, ds_reads issued BEFORE a barrier and
// lgkm-waited AFTER it, counted vmcnt(4) never 0 in loop.
#define MFMA_QUAD(MB, NB)                                                     \
    do {                                                                      \
        __builtin_amdgcn_s_setprio(1);                                        \
        _Pragma("unroll")                                                     \
        for (int mi_ = 0; mi_ < 4; ++mi_)                                     \
            _Pragma("unroll")                                                 \
            for (int ni_ = 0; ni_ < 2; ++ni_)                                 \
                _Pragma("unroll")                                             \
                for (int ks_ = 0; ks_ < 2; ++ks_)                             \
                    acc[(MB) + mi_][(NB) + ni_] =                             \
                        __builtin_amdgcn_mfma_f32_16x16x32_bf16(              \
                            Af[mi_][ks_], Bf[(NB) + ni_][ks_],                \
                            acc[(MB) + mi_][(NB) + ni_], 0, 0, 0);            \
        __builtin_amdgcn_s_setprio(0);                                        \
    } while (0)

__global__ __launch_bounds__(512, 2) void qkv_gemm_8ph(const short* __restrict__ A,
                                                       const short* __restrict__ Bt,
                                                       const float* __restrict__ bias,
                                                       short* __restrict__ Yqk,
                                                       short* __restrict__ Yv) {
    __shared__ short Asl[32768];   // [2][256][64] bf16 = 64 KiB
    __shared__ short Bsl[32768];   // [2][256][64] bf16 = 64 KiB

    const int tid  = threadIdx.x;
    const int w    = tid >> 6;        // wave 0..7
    const int lane = tid & 63;
    const int l16  = lane & 15;
    const int quad = lane >> 4;
    const int wm   = w >> 2;          // 0..1 (M)
    const int wn   = w & 3;           // 0..3 (N)
    const int ls   = lane >> 3;       // staging: row-in-slot 0..7
    const int lc   = lane & 7;        // staging: chunk 0..7
    const int fsw  = l16 & 7;         // frag-read swizzle

    // XCD-aware bijective swizzle: XCD x gets an 8(M) x 3(N) tile patch
    const int orig = blockIdx.y * 12 + blockIdx.x;
    const int xcd  = orig & 7;
    const int idx  = orig >> 3;                      // 0..23
    const int bM   = ((xcd & 1) << 3) + (idx & 7);   // 0..15
    const int bN   = (xcd >> 1) * 3 + (idx >> 3);    // 0..11
    const int m0   = bM << 8;
    const int n0   = bN << 8;

    const short* Ab = A  + (size_t)m0 * K_GEMM;
    const short* Bb = Bt + (size_t)n0 * K_GEMM;

    f32x4 acc[8][4];
#pragma unroll
    for (int i = 0; i < 8; ++i)
#pragma unroll
        for (int j = 0; j < 4; ++j) acc[i][j] = (f32x4){0.f, 0.f, 0.f, 0.f};

    auto stageA = [&](int unit, int tt, int sbuf) {
#pragma unroll
        for (int i = 0; i < 2; ++i) {
            const int u0 = (i * 8 + w) * 8;                       // unit row base
            const int tr = (u0 & 63) + ((u0 >> 6) << 7) + unit * 64;
            gl2lds16(Ab + (size_t)(tr + ls) * K_GEMM + tt * 64 + ((lc ^ ls) << 3),
                     &Asl[sbuf * 16384 + tr * 64]);
        }
    };
    auto stageB = [&](int unit, int tt, int sbuf) {
#pragma unroll
        for (int i = 0; i < 2; ++i) {
            const int u0 = (i * 8 + w) * 8;
            const int tr = (u0 & 31) + ((u0 >> 5) << 6) + unit * 32;
            gl2lds16(Bb + (size_t)(tr + ls) * K_GEMM + tt * 64 + ((lc ^ ls) << 3),
                     &Bsl[sbuf * 16384 + tr * 64]);
        }
    };
    auto rdA = [&](int ab, int mi, int ks) -> short8 {
        const int r = wm * 128 + mi * 16 + l16;
        return *(const short8*)&Asl[ab + r * 64 + ((ks * 4 + quad) ^ fsw) * 8];
    };
    auto rdB = [&](int ab, int ni, int ks) -> short8 {
        const int r = wn * 64 + ni * 16 + l16;
        return *(const short8*)&Bsl[ab + r * 64 + ((ks * 4 + quad) ^ fsw) * 8];
    };

    // prologue: tile 0 -> buf 0, order AE,BE,BO,AO; keep BO,AO in flight.
    stageA(0, 0, 0);
    stageB(0, 0, 0);
    stageB(1, 0, 0);
    stageA(1, 0, 0);
    WAITV4();
    SCB();
    BARRIER();
    SCB();

    for (int t = 0; t < 16; ++t) {
        const int buf = t & 1;
        const int sb  = buf ^ 1;
        const int tn  = (t + 1) & 15;     // t==15 stages dummy tile 0 (uniform waits)
        const int ab  = buf * 16384;

        short8 Af[4][2], Bf[4][2];

        // ================= phase 0: quadrant (miH0 x niH0) ===================
#pragma unroll
        for (int mi = 0; mi < 4; ++mi)
#pragma unroll
            for (int ks = 0; ks < 2; ++ks) Af[mi][ks] = rdA(ab, mi, ks);
#pragma unroll
        for (int ni = 0; ni < 2; ++ni)
#pragma unroll
            for (int ks = 0; ks < 2; ++ks) Bf[ni][ks] = rdB(ab, ni, ks);
        stageA(0, tn, sb);
        SCB(); BARRIER(); LGKM0(); SCB();
        MFMA_QUAD(0, 0);
        WAITV4();
        SCB(); BARRIER(); SCB();

        // ================= phase 1: quadrant (miH0 x niH1) ===================
#pragma unroll
        for (int ni = 2; ni < 4; ++ni)
#pragma unroll
            for (int ks = 0; ks < 2; ++ks) Bf[ni][ks] = rdB(ab, ni, ks);
        stageB(0, tn, sb);
        SCB(); BARRIER(); LGKM0(); SCB();
        MFMA_QUAD(0, 2);
        WAITV4();
        SCB(); BARRIER(); SCB();

        // ===== phase 2: quadrant (miH1 x niH0); Bf[0..1] reused from regs ====
#pragma unroll
        for (int mi = 0; mi < 4; ++mi)
#pragma unroll
            for (int ks = 0; ks < 2; ++ks) Af[mi][ks] = rdA(ab, 4 + mi, ks);
        stageB(1, tn, sb);
        SCB(); BARRIER(); LGKM0(); SCB();
        MFMA_QUAD(4, 0);
        SCB(); BARRIER(); SCB();          // no vmcnt here

        // ===== phase 3: quadrant (miH1 x niH1); Af + Bf[2..3] from regs ======
        stageA(1, tn, sb);
        SCB(); BARRIER(); SCB();
        MFMA_QUAD(4, 2);
        WAITV4();
        SCB(); BARRIER(); SCB();
    }
    WAITV0();   // drain dummy loads: no LDS-DMA may outlive the workgroup

    // ---- epilogue ----
    if (n0 >= 2 * CDIM) {
        // V block: write transposed, 4 consecutive rows packed per 8B store
#pragma unroll
        for (int mi = 0; mi < 8; ++mi) {
            int row0 = m0 + wm * 128 + mi * 16 + quad * 4;
#pragma unroll
            for (int ni = 0; ni < 4; ++ni) {
                int colg = n0 + wn * 64 + ni * 16 + l16;
                float bb = bias[colg];
                short4v pk;
#pragma unroll
                for (int r = 0; r < 4; ++r) pk[r] = bf16_rn(acc[mi][ni][r] + bb);
                *(short4v*)&Yv[(size_t)(colg - 2 * CDIM) * M_GEMM + row0] = pk;
            }
        }
    } else {
        // Q pre-scale folds BOTH 1/sqrt(64) and log2(e): attn does p = 2^s
        const float qs = (n0 < CDIM) ? 0.125f * 1.44269504f : 1.0f;
#pragma unroll
        for (int mi = 0; mi < 8; ++mi)
#pragma unroll
            for (int r = 0; r < 4; ++r) {
                int row = m0 + wm * 128 + mi * 16 + quad * 4 + r;
#pragma unroll
                for (int ni = 0; ni < 4; ++ni) {
                    int colg = n0 + wn * 64 + ni * 16 + l16;
                    Yqk[(size_t)row * QK_PITCH + colg] =
                        bf16_rn((acc[mi][ni][r] + bias[colg]) * qs);
                }
            }
    }
}

// ---------- Kernel 2: causal flash attention, R23 -----------------------------
// R23 = R22 tile body (swapped QK^T, in-register P, conflict-free hK) with a
// SEQUENTIAL TRIANGLE-PAIRING outer structure:
//   block bx processes q-strip bx (kv 0..bx) THEN q-strip 31-bx (kv 0..31-bx).
//   Every block = exactly 33 kv-tiles -> uniform length, no makespan tail.
// WHY: R22's counters showed nothing saturated (MFMA 14%, VALU 37%, LDS ~45%)
// and OccupancyPercent 21% with 4 one-strip blocks/CU whose lengths range
// 1..32: under co-residency a CU finishes at its LONGEST block, short blocks
// exit with nothing to backfill (exactly 4 assigned/CU), and the CU decays to
// a lone latency-bound block for a third of the kernel. Equal-length blocks
// (2/CU, both 33 tiles) give flat residency and a ~16% shorter critical path.
// Grid: (16, 16, 2) = 512 blocks, 4 waves each. LDS unchanged (32 KB).
__global__ __launch_bounds__(256) void attn_mfma(const short* __restrict__ qk,
                                                 const short* __restrict__ vT,
                                                 float* __restrict__ out) {
    const int b = blockIdx.z;
    const int h = blockIdx.y;
    const int bx = blockIdx.x;           // 0..15: strip pair (bx, 31-bx)
    const int tid = threadIdx.x;
    const int w = tid >> 6;
    const int lane = tid & 63;
    const int quad = lane >> 4;
    const int l16 = lane & 15;

    __shared__ short Ks[2][64 * 64];     // [buf][key][d], hK-swizzled   16 KB
    __shared__ short Vt[2][64 * 64];     // [buf][d][key], row&7-swizzled 16 KB

    // staging descriptors: issue p covers chunks cid = p*256 + w*64 + lane
    int koff[2], voff[2], ldso[2];
#pragma unroll
    for (int p = 0; p < 2; ++p) {
        int cid = p * 256 + w * 64 + lane;
        int row = cid >> 3;
        int hK = (row & 3) | (((row >> 3) & 1) << 2);   // conflict-free hash
        int cK = (cid & 7) ^ hK;
        int cV = (cid & 7) ^ (row & 7);
        koff[p] = row * QK_PITCH + cK * 8;
        voff[p] = row * M_GEMM + cV * 8;
        ldso[p] = (p * 256 + w * 64) * 8;    // wave-uniform chunk base (shorts)
    }

    const short* kb0 = qk + (size_t)(b * SEQ) * QK_PITCH + CDIM + h * HDIM;
    const short* vb0 = vT + (size_t)(h * HDIM) * M_GEMM + b * SEQ;

    const int ksl = l16 & 7;
    const int Fq = ((l16 >> 2) << 3) + (l16 & 3);   // quad-permuted K-row base

    for (int ph = 0; ph < 2; ++ph) {
        const int qt = ph ? (31 - bx) : bx;
        const int q0 = qt * 64;
        const int qglob = q0 + w * 16 + l16;     // this lane's q row (mask)

        // Q fragments (B-layout for swapped QK^T: B[k=d][n=q], lane l16 = q)
        const short* qrow = qk + (size_t)(b * SEQ + q0 + w * 16 + l16) * QK_PITCH + h * HDIM;
        short8 aq[2];
        aq[0] = *(const short8*)(qrow + quad * 8);
        aq[1] = *(const short8*)(qrow + 32 + quad * 8);

        float l_run = 0.f;                   // lane-scalar: q-row = l16
        f32x4 o_acc[4];
#pragma unroll
        for (int dt = 0; dt < 4; ++dt) o_acc[dt] = (f32x4){0.f, 0.f, 0.f, 0.f};

        // prologue: stage tile 0 into buf 0 (phase 0's trailing __syncthreads
        // guarantees no wave still reads LDS when ph=1 restages)
#pragma unroll
        for (int p = 0; p < 2; ++p) {
            gl2lds16(kb0 + koff[p], &Ks[0][ldso[p]]);
            gl2lds16(vb0 + voff[p], &Vt[0][ldso[p]]);
        }
        __syncthreads();                     // prologue staging drained

        for (int kt = 0; kt <= qt; ++kt) {
            const int cur = kt & 1;

            // prefetch tile kt+1 into the other buffer (overlaps compute)
            if (kt < qt) {
                const short* kbase = kb0 + (size_t)(kt + 1) * 64 * QK_PITCH;
                const short* vbase = vb0 + (kt + 1) * 64;
#pragma unroll
                for (int p = 0; p < 2; ++p) {
                    gl2lds16(kbase + koff[p], &Ks[cur ^ 1][ldso[p]]);
                    gl2lds16(vbase + voff[p], &Vt[cur ^ 1][ldso[p]]);
                }
            }

            const short* KsC = Ks[cur];
            const short* VtC = Vt[cur];

            // ---- swapped QK^T: s[nt][r] = S[key][q=l16], key per-lane ------
            f32x4 s[4];
#pragma unroll
            for (int nt = 0; nt < 4; ++nt) s[nt] = (f32x4){0.f, 0.f, 0.f, 0.f};
            __builtin_amdgcn_s_setprio(1);
#pragma unroll
            for (int nt = 0; nt < 4; ++nt) {
                const int F  = (nt >> 1) * 32 + (nt & 1) * 4 + Fq;
                const int hF = (F & 3) | (((F >> 3) & 1) << 2);   // conflict-free
#pragma unroll
                for (int ks = 0; ks < 2; ++ks) {
                    short8 kf = *(const short8*)&KsC[F * 64 + (((ks * 4 + quad) ^ hF) * 8)];
                    s[nt] = __builtin_amdgcn_mfma_f32_16x16x32_bf16(kf, aq[ks], s[nt], 0, 0, 0);
                }
            }
            __builtin_amdgcn_s_setprio(0);

            // ---- softmax in registers: p = 2^s, pack into PV A-frags -------
            short8 pa0, pa1;
            float lsum = 0.f;
            if (kt < qt) {                   // full tile
#pragma unroll
                for (int nt = 0; nt < 4; ++nt)
#pragma unroll
                    for (int r = 0; r < 4; ++r) {
                        float pp = __builtin_amdgcn_exp2f(s[nt][r]);
                        lsum += pp;
                        short pb = bf16_rn(pp);
                        if (nt < 2) pa0[(nt & 1) * 4 + r] = pb;
                        else        pa1[(nt & 1) * 4 + r] = pb;
                    }
            } else {                         // diagonal tile: causal mask
#pragma unroll
                for (int nt = 0; nt < 4; ++nt)
#pragma unroll
                    for (int r = 0; r < 4; ++r) {
                        int key = kt * 64 + (nt >> 1) * 32 + quad * 8 + (nt & 1) * 4 + r;
                        float pp = __builtin_amdgcn_exp2f(s[nt][r]);
                        pp = (key > qglob) ? 0.f : pp;
                        lsum += pp;
                        short pb = bf16_rn(pp);
                        if (nt < 2) pa0[(nt & 1) * 4 + r] = pb;
                        else        pa1[(nt & 1) * 4 + r] = pb;
                    }
            }
            l_run += lsum;

            // ---- PV: O[16 q][64 d] += P @ V; P is already the A-fragment ---
            __builtin_amdgcn_s_setprio(1);
#pragma unroll
            for (int dt = 0; dt < 4; ++dt)
#pragma unroll
                for (int ks = 0; ks < 2; ++ks) {
                    short8 bv = *(const short8*)&VtC[(dt * 16 + l16) * 64 +
                                                     ((ks * 4 + quad) ^ ksl) * 8];
                    o_acc[dt] = __builtin_amdgcn_mfma_f32_16x16x32_bf16(
                        ks ? pa1 : pa0, bv, o_acc[dt], 0, 0, 0);
                }
            __builtin_amdgcn_s_setprio(0);

            // one barrier/tile: drains prefetch + guards buffer reuse
            __syncthreads();
        }

        // ---- epilogue: reduce l (partial over quads), normalize, store -----
        float l = l_run;
        l += __shfl_xor(l, 16);
        l += __shfl_xor(l, 32);              // full row-sum for q=l16
#pragma unroll
        for (int r = 0; r < 4; ++r) {
            float lq = __shfl(l, quad * 4 + r);   // sum for q-row quad*4+r
            float inv = 1.f / lq;
            int row = q0 + w * 16 + quad * 4 + r;
            float* optr = out + (size_t)(b * SEQ + row) * CDIM + h * HDIM;
#pragma unroll
            for (int dt = 0; dt < 4; ++dt)
                optr[dt * 16 + l16] = o_acc[dt][r] * inv;
        }
    }
}

// ------------------------------- launch --------------------------------------
extern "C" void kernel_launch(void* const* d_in, const int* in_sizes, int n_in,
                              void* d_out, int out_size, void* d_ws, size_t ws_size,
                              hipStream_t stream) {
    const float* x      = (const float*)d_in[0];   // [B,T,C] fp32
    const float* w_attn = (const float*)d_in[1];   // [C,3C]  fp32
    const float* b_attn = (const float*)d_in[2];   // [3C]    fp32
    float* out = (float*)d_out;                    // [B,T,C] fp32

    // workspace: qk [4096][2048] 16.78MB | vT [1024][4096] 8.39MB | xb 8.39MB | wT 6.29MB
    short* qk  = (short*)d_ws;
    short* vT  = (short*)((char*)d_ws + 16777216);
    short* xb  = (short*)((char*)d_ws + 25165824);
    short* wT  = (short*)((char*)d_ws + 33554432);

    cvt_fused<<<2048 + 768, 256, 0, stream>>>(x, w_attn, xb, wT);

    dim3 g1(N_GEMM / 256, M_GEMM / 256);                                // (12,16)
    qkv_gemm_8ph<<<g1, 512, 0, stream>>>(xb, wT, b_attn, qk, vT);

    dim3 g2(SEQ / 128, NHEAD, BSZ);                                     // (16,16,2)
    attn_mfma<<<g2, 256, 0, stream>>>(qk, vT, out);
}

// Round 11
// 152.472 us; speedup vs baseline: 1.0375x; 1.0375x over previous
//
#include <hip/hip_runtime.h>
#include <hip/hip_bf16.h>

// Problem constants: B=2, T=2048, C=1024, H=16, D=64
#define BSZ 2
#define SEQ 2048
#define CDIM 1024
#define NHEAD 16
#define HDIM 64
#define M_GEMM (BSZ * SEQ)      // 4096
#define N_GEMM (3 * CDIM)       // 3072
#define K_GEMM CDIM             // 1024
#define QK_PITCH (2 * CDIM)     // 2048: qk buffer row pitch (Q|K only)

typedef __attribute__((ext_vector_type(8))) short short8;   // 8 bf16 = 16B
typedef __attribute__((ext_vector_type(4))) short short4v;  // 8B
typedef __attribute__((ext_vector_type(4))) float f32x4;

__device__ __forceinline__ short bf16_rn(float f) {
    unsigned u = __builtin_bit_cast(unsigned, f);
    u += 0x7FFF + ((u >> 16) & 1);          // round-to-nearest-even
    return (short)(u >> 16);
}

// async 16B global -> LDS (wave-uniform LDS base; HW adds lane*16)
__device__ __forceinline__ void gl2lds16(const short* g, short* l) {
    __builtin_amdgcn_global_load_lds(
        (const __attribute__((address_space(1))) unsigned int*)g,
        (__attribute__((address_space(3))) unsigned int*)l, 16, 0, 0);
}

// bare counted waits (NO "memory" clobber: that forces a full vmcnt0/lgkmcnt0
// drain by SIInsertWaitcnts). Ordering pinned with sched_barrier(0) instead.
#define WAITV2() asm volatile("s_waitcnt vmcnt(2)")
#define WAITV3() asm volatile("s_waitcnt vmcnt(3)")
#define WAITV0() asm volatile("s_waitcnt vmcnt(0)")
#define LGKM0()  asm volatile("s_waitcnt lgkmcnt(0)")
#define SCB()    __builtin_amdgcn_sched_barrier(0)
#define BARRIER() __builtin_amdgcn_s_barrier()

// ------------- Kernel 0: fused fp32->bf16 conversions ------------------------
// blocks [0, 2048): x -> xb (same layout). blocks [2048, 2816): W -> W^T tiles.
__global__ __launch_bounds__(256) void cvt_fused(const float* __restrict__ X,
                                                 const float* __restrict__ W,
                                                 short* __restrict__ Xb,
                                                 short* __restrict__ WT) {
    const int tid = threadIdx.x;
    if (blockIdx.x < 2048) {
        size_t idx = ((size_t)blockIdx.x * 256 + tid) * 8;
        float4 a = *(const float4*)&X[idx];
        float4 b = *(const float4*)&X[idx + 4];
        short8 o;
        o[0] = bf16_rn(a.x); o[1] = bf16_rn(a.y); o[2] = bf16_rn(a.z); o[3] = bf16_rn(a.w);
        o[4] = bf16_rn(b.x); o[5] = bf16_rn(b.y); o[6] = bf16_rn(b.z); o[7] = bf16_rn(b.w);
        *(short8*)&Xb[idx] = o;
        return;
    }
    __shared__ short T[64][72];
    const int bid = blockIdx.x - 2048;          // 0..767
    const int n0 = (bid % 48) * 64;
    const int k0 = (bid / 48) * 64;
#pragma unroll
    for (int pass = 0; pass < 4; ++pass) {
        int i = pass * 256 + tid;
        int kr = i >> 4;
        int n4 = i & 15;
        float4 v = *(const float4*)&W[(size_t)(k0 + kr) * N_GEMM + n0 + n4 * 4];
        T[n4 * 4 + 0][kr] = bf16_rn(v.x);
        T[n4 * 4 + 1][kr] = bf16_rn(v.y);
        T[n4 * 4 + 2][kr] = bf16_rn(v.z);
        T[n4 * 4 + 3][kr] = bf16_rn(v.w);
    }
    __syncthreads();
#pragma unroll
    for (int pass = 0; pass < 2; ++pass) {
        int o = pass * 256 + tid;
        int nr = o >> 3;
        int c8 = o & 7;
        *(short8*)&WT[(size_t)(n0 + nr) * K_GEMM + k0 + c8 * 8] =
            *(const short8*)&T[nr][c8 * 8];
    }
}

// -------- Kernel 1: qkv = x @ W + b — R26 (= R25 resubmitted): 256x192 tile,
// 256 blocks = 1/CU. R25 never executed (container failed twice — infra-flake
// signature, harness push times ballooned to 866s; full deadlock/address audit
// found no defect). Design:
//  - staging units == phase read-sets (R19 principle; R24's contiguous units
//    were the correctness bug):
//    A unit u (interleaved): u0 = rows 0-63 U 128-191 (every wave's mi0-3
//    rows), u1 = 64-127 U 192-255. Identity LDS rows.
//    BE = ph0 read-set {wn*48+0..31} (128 rows) at LDS rows j = wn*32+s;
//    BO = ph1 read-set {wn*48+32..47} (64 rows) at j = 128+wn*16+s.
//    j&7 == global-row&7 == l16&7, so the chunk-XOR swizzle carries over.
//  - 8 waves (2M x 4N), per-wave C = 128x48: acc[8][3]. LDS 112 KiB static.
//  - phases: ph0 mi0-3 x ni0-1 (16 MFMA), ph1 mi0-3 x ni2 (8, Af reused),
//    ph2 mi4-7 x ni0-1 (16, Bf reused), ph3 mi4-7 x ni2 (8, all reused).
//  - stage placement (into buf^1): ph0->A0', ph1->BE', ph2->A1', ph3->BO'.
//    vmcnt ledger (FIFO; per wave; issue order A0'(2) BE'(2) A1'(2) BO'(1)):
//      entering ph0(t): outstanding = A1(t):2, BO(t):1
//      ph0 reads A0,BE(t) (drained end-ph3(t-1)); issues A0'(2) -> out 5
//      end-ph0 vmcnt(2): drains A1(t)+BO(t)  [ph2 reads A1, ph1 reads BO]
//      ph1 issues BE'(2) -> 4; ph2 issues A1'(2) -> 6; ph3 issues BO'(1) -> 7
//      end-ph3 vmcnt(3): drains A0'+BE' [read in ph0(t+1)]; leaves A1',BO'
//    Counted waits always precede a barrier (cross-wave publication); never 0.
//  - last iter stages dummy tile 0 (uniform waits); WAITV0 after the loop.
//  - BN=192: the Q|K vs V epilogue boundary (col 2048) is 16-aligned, so the
//    epilogue branches per 16-col group (wave-uniform).
__global__ __launch_bounds__(512, 2) void qkv_gemm_8ph(const short* __restrict__ A,
                                                       const short* __restrict__ Bt,
                                                       const float* __restrict__ bias,
                                                       short* __restrict__ Yqk,
                                                       short* __restrict__ Yv) {
    __shared__ short Asl[32768];   // [2][256][64] bf16 = 64 KiB (identity rows)
    __shared__ short Bsl[24576];   // [2][192][64] bf16 = 48 KiB (permuted rows)

    const int tid  = threadIdx.x;
    const int w    = tid >> 6;        // wave 0..7
    const int lane = tid & 63;
    const int l16  = lane & 15;
    const int quad = lane >> 4;
    const int wm   = w >> 2;          // 0..1 (M)
    const int wn   = w & 3;           // 0..3 (N)
    const int ls   = lane >> 3;       // staging: row-in-octet 0..7
    const int lc   = lane & 7;        // staging: chunk 0..7
    const int fsw  = l16 & 7;         // frag-read swizzle

    // XCD-aware bijective swizzle: XCD x gets an 8(M) x 4(N) tile patch.
    const int orig = blockIdx.y * 16 + blockIdx.x;   // 0..255
    const int xcd  = orig & 7;
    const int idx  = orig >> 3;                      // 0..31
    const int bM   = ((xcd & 1) << 3) + (idx & 7);   // 0..15
    const int bN   = (xcd >> 1) * 4 + (idx >> 3);    // 0..15
    const int m0   = bM << 8;        // *256
    const int n0   = bN * 192;

    const short* Ab = A  + (size_t)m0 * K_GEMM;
    const short* Bb = Bt + (size_t)n0 * K_GEMM;

    f32x4 acc[8][3];
#pragma unroll
    for (int i = 0; i < 8; ++i)
#pragma unroll
        for (int j = 0; j < 3; ++j) acc[i][j] = (f32x4){0.f, 0.f, 0.f, 0.f};

    // A unit (interleaved, R19 form): unit0 = rows 0-63 U 128-191 (= every
    // wave's mi0-3 rows), unit1 = rows 64-127 U 192-255. 2 issues/thread.
    auto stageA = [&](int unit, int tt, int sbuf) {
#pragma unroll
        for (int i = 0; i < 2; ++i) {
            const int u0 = (i * 8 + w) * 8;                       // 0..120
            const int tr = (u0 & 63) + ((u0 >> 6) << 7) + unit * 64;
            gl2lds16(Ab + (size_t)(tr + ls) * K_GEMM + tt * 64 + ((lc ^ ls) << 3),
                     &Asl[sbuf * 16384 + tr * 64]);
        }
    };
    // BE unit: ph0 read-set, 128 rows, LDS rows j = wn_blk*32 + s (s<32).
    auto stageBE = [&](int tt, int sbuf) {
#pragma unroll
        for (int i = 0; i < 2; ++i) {
            const int jb = i * 64 + w * 8;               // LDS row base (mult 8)
            const int gr = (jb >> 5) * 48 + (jb & 31);   // global row base
            gl2lds16(Bb + (size_t)(gr + ls) * K_GEMM + tt * 64 + ((lc ^ ls) << 3),
                     &Bsl[sbuf * 12288 + jb * 64]);
        }
    };
    // BO unit: ph1 read-set, 64 rows, LDS rows j = 128 + wn_blk*16 + s (s<16).
    auto stageBO = [&](int tt, int sbuf) {
        const int t8 = w * 8;
        const int jb = 128 + t8;                         // LDS row base (mult 8)
        const int gr = (t8 >> 4) * 48 + 32 + (t8 & 15);  // global row base
        gl2lds16(Bb + (size_t)(gr + ls) * K_GEMM + tt * 64 + ((lc ^ ls) << 3),
                 &Bsl[sbuf * 12288 + jb * 64]);
    };
    auto rdA = [&](int ab, int mi, int ks) -> short8 {
        const int r = wm * 128 + mi * 16 + l16;          // identity LDS row
        return *(const short8*)&Asl[ab + r * 64 + ((ks * 4 + quad) ^ fsw) * 8];
    };
    auto rdB = [&](int bb, int ni, int ks) -> short8 {
        const int j = (ni < 2) ? (wn * 32 + ni * 16 + l16)   // BE region
                               : (128 + wn * 16 + l16);      // BO region
        return *(const short8*)&Bsl[bb + j * 64 + ((ks * 4 + quad) ^ fsw) * 8];
    };

    // prologue: tile 0 -> buf 0. Issue order A0,BE,A1,BO (= steady state);
    // drain A0+BE, leave A1(2)+BO(1) in flight.
    stageA(0, 0, 0);
    stageBE(0, 0);
    stageA(1, 0, 0);
    stageBO(0, 0);
    WAITV3();
    SCB(); BARRIER(); SCB();

    for (int t = 0; t < 16; ++t) {
        const int buf = t & 1;
        const int sb  = buf ^ 1;
        const int tn  = (t + 1) & 15;     // t==15 stages dummy tile 0
        const int ab  = buf * 16384;
        const int bb  = buf * 12288;

        short8 Af[4][2], Bf[3][2];

        // ===== phase 0: mi0-3 x ni0-1 (16 MFMA); stage A0(t+1) ==============
#pragma unroll
        for (int mi = 0; mi < 4; ++mi)
#pragma unroll
            for (int ks = 0; ks < 2; ++ks) Af[mi][ks] = rdA(ab, mi, ks);
#pragma unroll
        for (int ni = 0; ni < 2; ++ni)
#pragma unroll
            for (int ks = 0; ks < 2; ++ks) Bf[ni][ks] = rdB(bb, ni, ks);
        stageA(0, tn, sb);
        SCB(); BARRIER(); LGKM0(); SCB();
        __builtin_amdgcn_s_setprio(1);
#pragma unroll
        for (int mi = 0; mi < 4; ++mi)
#pragma unroll
            for (int ni = 0; ni < 2; ++ni)
#pragma unroll
                for (int ks = 0; ks < 2; ++ks)
                    acc[mi][ni] = __builtin_amdgcn_mfma_f32_16x16x32_bf16(
                        Af[mi][ks], Bf[ni][ks], acc[mi][ni], 0, 0, 0);
        __builtin_amdgcn_s_setprio(0);
        WAITV2();
        SCB(); BARRIER(); SCB();

        // ===== phase 1: mi0-3 x ni2 (8 MFMA, Af reused); stage BE(t+1) ======
#pragma unroll
        for (int ks = 0; ks < 2; ++ks) Bf[2][ks] = rdB(bb, 2, ks);
        stageBE(tn, sb);
        SCB(); BARRIER(); LGKM0(); SCB();
        __builtin_amdgcn_s_setprio(1);
#pragma unroll
        for (int mi = 0; mi < 4; ++mi)
#pragma unroll
            for (int ks = 0; ks < 2; ++ks)
                acc[mi][2] = __builtin_amdgcn_mfma_f32_16x16x32_bf16(
                    Af[mi][ks], Bf[2][ks], acc[mi][2], 0, 0, 0);
        __builtin_amdgcn_s_setprio(0);
        SCB(); BARRIER(); SCB();          // no vmcnt here

        // ===== phase 2: mi4-7 x ni0-1 (16 MFMA, Bf reused); stage A1(t+1) ===
#pragma unroll
        for (int mi = 0; mi < 4; ++mi)
#pragma unroll
            for (int ks = 0; ks < 2; ++ks) Af[mi][ks] = rdA(ab, 4 + mi, ks);
        stageA(1, tn, sb);
        SCB(); BARRIER(); LGKM0(); SCB();
        __builtin_amdgcn_s_setprio(1);
#pragma unroll
        for (int mi = 0; mi < 4; ++mi)
#pragma unroll
            for (int ni = 0; ni < 2; ++ni)
#pragma unroll
                for (int ks = 0; ks < 2; ++ks)
                    acc[4 + mi][ni] = __builtin_amdgcn_mfma_f32_16x16x32_bf16(
                        Af[mi][ks], Bf[ni][ks], acc[4 + mi][ni], 0, 0, 0);
        __builtin_amdgcn_s_setprio(0);
        SCB(); BARRIER(); SCB();          // no vmcnt here

        // ===== phase 3: mi4-7 x ni2 (8 MFMA, all regs reused); stage BO =====
        stageBO(tn, sb);
        SCB(); BARRIER(); SCB();
        __builtin_amdgcn_s_setprio(1);
#pragma unroll
        for (int mi = 0; mi < 4; ++mi)
#pragma unroll
            for (int ks = 0; ks < 2; ++ks)
                acc[4 + mi][2] = __builtin_amdgcn_mfma_f32_16x16x32_bf16(
                    Af[mi][ks], Bf[2][ks], acc[4 + mi][2], 0, 0, 0);
        __builtin_amdgcn_s_setprio(0);
        WAITV3();
        SCB(); BARRIER(); SCB();
    }
    WAITV0();   // drain remaining/dummy loads: no LDS-DMA outlives the block

    // ---- epilogue: per 16-col group, Q|K (scaled bf16) or V (transposed) ----
    const float log2e8 = 0.125f * 1.44269504f;
#pragma unroll
    for (int mi = 0; mi < 8; ++mi) {
#pragma unroll
        for (int ni = 0; ni < 3; ++ni) {
            const int colg = n0 + wn * 48 + ni * 16 + l16;
            const float bb2 = bias[colg];
            if (colg >= 2 * CDIM) {
                // V: write transposed, 4 consecutive rows packed per 8B store
                const int row0 = m0 + wm * 128 + mi * 16 + quad * 4;
                short4v pk;
#pragma unroll
                for (int r = 0; r < 4; ++r) pk[r] = bf16_rn(acc[mi][ni][r] + bb2);
                *(short4v*)&Yv[(size_t)(colg - 2 * CDIM) * M_GEMM + row0] = pk;
            } else {
                // Q pre-scale folds 1/sqrt(64) and log2(e): attn does p = 2^s
                const float qs = (colg < CDIM) ? log2e8 : 1.0f;
#pragma unroll
                for (int r = 0; r < 4; ++r) {
                    const int row = m0 + wm * 128 + mi * 16 + quad * 4 + r;
                    Yqk[(size_t)row * QK_PITCH + colg] =
                        bf16_rn((acc[mi][ni][r] + bb2) * qs);
                }
            }
        }
    }
}

// ---------- Kernel 2: causal flash attention (R22 winner, verbatim) ----------
// 64 q-rows/block, grid (32,16,2), swapped QK^T with in-register P,
// conflict-free hK(row) = (row&3) | (((row>>3)&1)<<2), coset-balanced qt.
__global__ __launch_bounds__(256) void attn_mfma(const short* __restrict__ qk,
                                                 const short* __restrict__ vT,
                                                 float* __restrict__ out) {
    const int b = blockIdx.z;
    const int h = blockIdx.y;
    const int bx = blockIdx.x;           // 0..31
    const int u = h + 16 * b;            // 0..31
    const int band = u >> 3;             // 0..3
    const int base = (band & 2) ? ((bx + 16) & 31) : bx;
    const int qt = (band & 1) ? (31 - base) : base;
    const int tid = threadIdx.x;
    const int w = tid >> 6;
    const int lane = tid & 63;
    const int quad = lane >> 4;
    const int l16 = lane & 15;
    const int q0 = qt * 64;

    __shared__ short Ks[2][64 * 64];     // [buf][key][d], hK-swizzled   16 KB
    __shared__ short Vt[2][64 * 64];     // [buf][d][key], row&7-swizzled 16 KB

    // staging descriptors: issue p covers chunks cid = p*256 + w*64 + lane
    int koff[2], voff[2], ldso[2];
#pragma unroll
    for (int p = 0; p < 2; ++p) {
        int cid = p * 256 + w * 64 + lane;
        int row = cid >> 3;
        int hK = (row & 3) | (((row >> 3) & 1) << 2);   // conflict-free hash
        int cK = (cid & 7) ^ hK;
        int cV = (cid & 7) ^ (row & 7);
        koff[p] = row * QK_PITCH + cK * 8;
        voff[p] = row * M_GEMM + cV * 8;
        ldso[p] = (p * 256 + w * 64) * 8;    // wave-uniform chunk base (shorts)
    }

    // Q fragments (B-layout for swapped QK^T: B[k=d][n=q], lane l16 = q)
    const short* qrow = qk + (size_t)(b * SEQ + q0 + w * 16 + l16) * QK_PITCH + h * HDIM;
    short8 aq[2];
    aq[0] = *(const short8*)(qrow + quad * 8);
    aq[1] = *(const short8*)(qrow + 32 + quad * 8);

    float l_run = 0.f;                   // lane-scalar: q-row = l16
    f32x4 o_acc[4];
#pragma unroll
    for (int dt = 0; dt < 4; ++dt) o_acc[dt] = (f32x4){0.f, 0.f, 0.f, 0.f};

    const int qglob = q0 + w * 16 + l16; // this lane's q row (for mask)
    const short* kb0 = qk + (size_t)(b * SEQ) * QK_PITCH + CDIM + h * HDIM;
    const short* vb0 = vT + (size_t)(h * HDIM) * M_GEMM + b * SEQ;

    const int ksl = l16 & 7;

    // permuted K-row per nt-block: F(nt,l16) (quad-permuted base)
    const int Fq = ((l16 >> 2) << 3) + (l16 & 3);

    // prologue: stage tile 0 into buf 0
#pragma unroll
    for (int p = 0; p < 2; ++p) {
        gl2lds16(kb0 + koff[p], &Ks[0][ldso[p]]);
        gl2lds16(vb0 + voff[p], &Vt[0][ldso[p]]);
    }
    __syncthreads();                     // prologue staging drained

    for (int kt = 0; kt <= qt; ++kt) {
        const int cur = kt & 1;

        // prefetch tile kt+1 into the other buffer (overlaps compute)
        if (kt < qt) {
            const short* kbase = kb0 + (size_t)(kt + 1) * 64 * QK_PITCH;
            const short* vbase = vb0 + (kt + 1) * 64;
#pragma unroll
            for (int p = 0; p < 2; ++p) {
                gl2lds16(kbase + koff[p], &Ks[cur ^ 1][ldso[p]]);
                gl2lds16(vbase + voff[p], &Vt[cur ^ 1][ldso[p]]);
            }
        }

        const short* KsC = Ks[cur];
        const short* VtC = Vt[cur];

        // ---- swapped QK^T: s[nt][r] = S[key][q=l16], key per-lane mapped ----
        f32x4 s[4];
#pragma unroll
        for (int nt = 0; nt < 4; ++nt) s[nt] = (f32x4){0.f, 0.f, 0.f, 0.f};
        __builtin_amdgcn_s_setprio(1);
#pragma unroll
        for (int nt = 0; nt < 4; ++nt) {
            const int F  = (nt >> 1) * 32 + (nt & 1) * 4 + Fq;
            const int hF = (F & 3) | (((F >> 3) & 1) << 2);   // conflict-free
#pragma unroll
            for (int ks = 0; ks < 2; ++ks) {
                short8 kf = *(const short8*)&KsC[F * 64 + (((ks * 4 + quad) ^ hF) * 8)];
                s[nt] = __builtin_amdgcn_mfma_f32_16x16x32_bf16(kf, aq[ks], s[nt], 0, 0, 0);
            }
        }
        __builtin_amdgcn_s_setprio(0);

        // ---- softmax in registers: p = 2^s, pack straight into PV A-frags --
        short8 pa0, pa1;
        float lsum = 0.f;
        if (kt < qt) {                   // full tile
#pragma unroll
            for (int nt = 0; nt < 4; ++nt)
#pragma unroll
                for (int r = 0; r < 4; ++r) {
                    float pp = __builtin_amdgcn_exp2f(s[nt][r]);
                    lsum += pp;
                    short pb = bf16_rn(pp);
                    if (nt < 2) pa0[(nt & 1) * 4 + r] = pb;
                    else        pa1[(nt & 1) * 4 + r] = pb;
                }
        } else {                         // diagonal tile: causal mask
#pragma unroll
            for (int nt = 0; nt < 4; ++nt)
#pragma unroll
                for (int r = 0; r < 4; ++r) {
                    int key = kt * 64 + (nt >> 1) * 32 + quad * 8 + (nt & 1) * 4 + r;
                    float pp = __builtin_amdgcn_exp2f(s[nt][r]);
                    pp = (key > qglob) ? 0.f : pp;
                    lsum += pp;
                    short pb = bf16_rn(pp);
                    if (nt < 2) pa0[(nt & 1) * 4 + r] = pb;
                    else        pa1[(nt & 1) * 4 + r] = pb;
                }
        }
        l_run += lsum;

        // ---- PV: O[16 q][64 d] += P @ V; P is already the A-fragment ------
        __builtin_amdgcn_s_setprio(1);
#pragma unroll
        for (int dt = 0; dt < 4; ++dt)
#pragma unroll
            for (int ks = 0; ks < 2; ++ks) {
                short8 bv = *(const short8*)&VtC[(dt * 16 + l16) * 64 +
                                                 ((ks * 4 + quad) ^ ksl) * 8];
                o_acc[dt] = __builtin_amdgcn_mfma_f32_16x16x32_bf16(
                    ks ? pa1 : pa0, bv, o_acc[dt], 0, 0, 0);
            }
        __builtin_amdgcn_s_setprio(0);

        // one barrier/tile: drains prefetch + guards buffer reuse
        __syncthreads();
    }

    // ---- epilogue: l lives at q=l16 (partial over quads) -> reduce, redist -
    float l = l_run;
    l += __shfl_xor(l, 16);
    l += __shfl_xor(l, 32);              // now full row-sum for q=l16, all quads
#pragma unroll
    for (int r = 0; r < 4; ++r) {
        float lq = __shfl(l, quad * 4 + r);   // sum for q-row quad*4+r
        float inv = 1.f / lq;
        int row = q0 + w * 16 + quad * 4 + r;
        float* optr = out + (size_t)(b * SEQ + row) * CDIM + h * HDIM;
#pragma unroll
        for (int dt = 0; dt < 4; ++dt)
            optr[dt * 16 + l16] = o_acc[dt][r] * inv;
    }
}

// ------------------------------- launch --------------------------------------
extern "C" void kernel_launch(void* const* d_in, const int* in_sizes, int n_in,
                              void* d_out, int out_size, void* d_ws, size_t ws_size,
                              hipStream_t stream) {
    const float* x      = (const float*)d_in[0];   // [B,T,C] fp32
    const float* w_attn = (const float*)d_in[1];   // [C,3C]  fp32
    const float* b_attn = (const float*)d_in[2];   // [3C]    fp32
    float* out = (float*)d_out;                    // [B,T,C] fp32

    // workspace: qk [4096][2048] 16.78MB | vT [1024][4096] 8.39MB | xb 8.39MB | wT 6.29MB
    short* qk  = (short*)d_ws;
    short* vT  = (short*)((char*)d_ws + 16777216);
    short* xb  = (short*)((char*)d_ws + 25165824);
    short* wT  = (short*)((char*)d_ws + 33554432);

    cvt_fused<<<2048 + 768, 256, 0, stream>>>(x, w_attn, xb, wT);

    dim3 g1(N_GEMM / 192, M_GEMM / 256);                                // (16,16)
    qkv_gemm_8ph<<<g1, 512, 0, stream>>>(xb, wT, b_attn, qk, vT);

    dim3 g2(SEQ / 64, NHEAD, BSZ);                                      // (32,16,2)
    attn_mfma<<<g2, 256, 0, stream>>>(qk, vT, out);
}

// Round 12
// 150.736 us; speedup vs baseline: 1.0495x; 1.0115x over previous
//
#include <hip/hip_runtime.h>
#include <hip/hip_bf16.h>

// Problem constants: B=2, T=2048, C=1024, H=16, D=64
#define BSZ 2
#define SEQ 2048
#define CDIM 1024
#define NHEAD 16
#define HDIM 64
#define M_GEMM (BSZ * SEQ)      // 4096
#define N_GEMM (3 * CDIM)       // 3072
#define K_GEMM CDIM             // 1024
#define QK_PITCH (2 * CDIM)     // 2048: qk buffer row pitch (Q|K only)

typedef __attribute__((ext_vector_type(8))) short short8;   // 8 bf16 = 16B
typedef __attribute__((ext_vector_type(4))) short short4v;  // 8B
typedef __attribute__((ext_vector_type(4))) float f32x4;

__device__ __forceinline__ short bf16_rn(float f) {
    unsigned u = __builtin_bit_cast(unsigned, f);
    u += 0x7FFF + ((u >> 16) & 1);          // round-to-nearest-even
    return (short)(u >> 16);
}

// async 16B global -> LDS (wave-uniform LDS base; HW adds lane*16)
__device__ __forceinline__ void gl2lds16(const short* g, short* l) {
    __builtin_amdgcn_global_load_lds(
        (const __attribute__((address_space(1))) unsigned int*)g,
        (__attribute__((address_space(3))) unsigned int*)l, 16, 0, 0);
}

// bare counted waits (NO "memory" clobber: that forces a full vmcnt0/lgkmcnt0
// drain by SIInsertWaitcnts). Ordering pinned with sched_barrier(0) instead.
#define WAITV2() asm volatile("s_waitcnt vmcnt(2)")
#define WAITV3() asm volatile("s_waitcnt vmcnt(3)")
#define WAITV0() asm volatile("s_waitcnt vmcnt(0)")
#define LGKM0()  asm volatile("s_waitcnt lgkmcnt(0)")
#define SCB()    __builtin_amdgcn_sched_barrier(0)
#define BARRIER() __builtin_amdgcn_s_barrier()

// ------------- Kernel 0: fused fp32->bf16 conversions ------------------------
// blocks [0, 2048): x -> xb (same layout). blocks [2048, 2816): W -> W^T tiles.
__global__ __launch_bounds__(256) void cvt_fused(const float* __restrict__ X,
                                                 const float* __restrict__ W,
                                                 short* __restrict__ Xb,
                                                 short* __restrict__ WT) {
    const int tid = threadIdx.x;
    if (blockIdx.x < 2048) {
        size_t idx = ((size_t)blockIdx.x * 256 + tid) * 8;
        float4 a = *(const float4*)&X[idx];
        float4 b = *(const float4*)&X[idx + 4];
        short8 o;
        o[0] = bf16_rn(a.x); o[1] = bf16_rn(a.y); o[2] = bf16_rn(a.z); o[3] = bf16_rn(a.w);
        o[4] = bf16_rn(b.x); o[5] = bf16_rn(b.y); o[6] = bf16_rn(b.z); o[7] = bf16_rn(b.w);
        *(short8*)&Xb[idx] = o;
        return;
    }
    __shared__ short T[64][72];
    const int bid = blockIdx.x - 2048;          // 0..767
    const int n0 = (bid % 48) * 64;
    const int k0 = (bid / 48) * 64;
#pragma unroll
    for (int pass = 0; pass < 4; ++pass) {
        int i = pass * 256 + tid;
        int kr = i >> 4;
        int n4 = i & 15;
        float4 v = *(const float4*)&W[(size_t)(k0 + kr) * N_GEMM + n0 + n4 * 4];
        T[n4 * 4 + 0][kr] = bf16_rn(v.x);
        T[n4 * 4 + 1][kr] = bf16_rn(v.y);
        T[n4 * 4 + 2][kr] = bf16_rn(v.z);
        T[n4 * 4 + 3][kr] = bf16_rn(v.w);
    }
    __syncthreads();
#pragma unroll
    for (int pass = 0; pass < 2; ++pass) {
        int o = pass * 256 + tid;
        int nr = o >> 3;
        int c8 = o & 7;
        *(short8*)&WT[(size_t)(n0 + nr) * K_GEMM + k0 + c8 * 8] =
            *(const short8*)&T[nr][c8 * 8];
    }
}

// -------- Kernel 1: qkv = x @ W + b — R26 GEMM (verbatim): 256x192 tile,
// 256 blocks = 1/CU, staging units == phase read-sets, counted vmcnt ledger.
__global__ __launch_bounds__(512, 2) void qkv_gemm_8ph(const short* __restrict__ A,
                                                       const short* __restrict__ Bt,
                                                       const float* __restrict__ bias,
                                                       short* __restrict__ Yqk,
                                                       short* __restrict__ Yv) {
    __shared__ short Asl[32768];   // [2][256][64] bf16 = 64 KiB (identity rows)
    __shared__ short Bsl[24576];   // [2][192][64] bf16 = 48 KiB (permuted rows)

    const int tid  = threadIdx.x;
    const int w    = tid >> 6;        // wave 0..7
    const int lane = tid & 63;
    const int l16  = lane & 15;
    const int quad = lane >> 4;
    const int wm   = w >> 2;          // 0..1 (M)
    const int wn   = w & 3;           // 0..3 (N)
    const int ls   = lane >> 3;       // staging: row-in-octet 0..7
    const int lc   = lane & 7;        // staging: chunk 0..7
    const int fsw  = l16 & 7;         // frag-read swizzle

    // XCD-aware bijective swizzle: XCD x gets an 8(M) x 4(N) tile patch.
    const int orig = blockIdx.y * 16 + blockIdx.x;   // 0..255
    const int xcd  = orig & 7;
    const int idx  = orig >> 3;                      // 0..31
    const int bM   = ((xcd & 1) << 3) + (idx & 7);   // 0..15
    const int bN   = (xcd >> 1) * 4 + (idx >> 3);    // 0..15
    const int m0   = bM << 8;        // *256
    const int n0   = bN * 192;

    const short* Ab = A  + (size_t)m0 * K_GEMM;
    const short* Bb = Bt + (size_t)n0 * K_GEMM;

    f32x4 acc[8][3];
#pragma unroll
    for (int i = 0; i < 8; ++i)
#pragma unroll
        for (int j = 0; j < 3; ++j) acc[i][j] = (f32x4){0.f, 0.f, 0.f, 0.f};

    // A unit (interleaved, R19 form): unit0 = rows 0-63 U 128-191 (= every
    // wave's mi0-3 rows), unit1 = rows 64-127 U 192-255. 2 issues/thread.
    auto stageA = [&](int unit, int tt, int sbuf) {
#pragma unroll
        for (int i = 0; i < 2; ++i) {
            const int u0 = (i * 8 + w) * 8;                       // 0..120
            const int tr = (u0 & 63) + ((u0 >> 6) << 7) + unit * 64;
            gl2lds16(Ab + (size_t)(tr + ls) * K_GEMM + tt * 64 + ((lc ^ ls) << 3),
                     &Asl[sbuf * 16384 + tr * 64]);
        }
    };
    // BE unit: ph0 read-set, 128 rows, LDS rows j = wn_blk*32 + s (s<32).
    auto stageBE = [&](int tt, int sbuf) {
#pragma unroll
        for (int i = 0; i < 2; ++i) {
            const int jb = i * 64 + w * 8;               // LDS row base (mult 8)
            const int gr = (jb >> 5) * 48 + (jb & 31);   // global row base
            gl2lds16(Bb + (size_t)(gr + ls) * K_GEMM + tt * 64 + ((lc ^ ls) << 3),
                     &Bsl[sbuf * 12288 + jb * 64]);
        }
    };
    // BO unit: ph1 read-set, 64 rows, LDS rows j = 128 + wn_blk*16 + s (s<16).
    auto stageBO = [&](int tt, int sbuf) {
        const int t8 = w * 8;
        const int jb = 128 + t8;                         // LDS row base (mult 8)
        const int gr = (t8 >> 4) * 48 + 32 + (t8 & 15);  // global row base
        gl2lds16(Bb + (size_t)(gr + ls) * K_GEMM + tt * 64 + ((lc ^ ls) << 3),
                 &Bsl[sbuf * 12288 + jb * 64]);
    };
    auto rdA = [&](int ab, int mi, int ks) -> short8 {
        const int r = wm * 128 + mi * 16 + l16;          // identity LDS row
        return *(const short8*)&Asl[ab + r * 64 + ((ks * 4 + quad) ^ fsw) * 8];
    };
    auto rdB = [&](int bb, int ni, int ks) -> short8 {
        const int j = (ni < 2) ? (wn * 32 + ni * 16 + l16)   // BE region
                               : (128 + wn * 16 + l16);      // BO region
        return *(const short8*)&Bsl[bb + j * 64 + ((ks * 4 + quad) ^ fsw) * 8];
    };

    // prologue: tile 0 -> buf 0. Issue order A0,BE,A1,BO (= steady state);
    // drain A0+BE, leave A1(2)+BO(1) in flight.
    stageA(0, 0, 0);
    stageBE(0, 0);
    stageA(1, 0, 0);
    stageBO(0, 0);
    WAITV3();
    SCB(); BARRIER(); SCB();

    for (int t = 0; t < 16; ++t) {
        const int buf = t & 1;
        const int sb  = buf ^ 1;
        const int tn  = (t + 1) & 15;     // t==15 stages dummy tile 0
        const int ab  = buf * 16384;
        const int bb  = buf * 12288;

        short8 Af[4][2], Bf[3][2];

        // ===== phase 0: mi0-3 x ni0-1 (16 MFMA); stage A0(t+1) ==============
#pragma unroll
        for (int mi = 0; mi < 4; ++mi)
#pragma unroll
            for (int ks = 0; ks < 2; ++ks) Af[mi][ks] = rdA(ab, mi, ks);
#pragma unroll
        for (int ni = 0; ni < 2; ++ni)
#pragma unroll
            for (int ks = 0; ks < 2; ++ks) Bf[ni][ks] = rdB(bb, ni, ks);
        stageA(0, tn, sb);
        SCB(); BARRIER(); LGKM0(); SCB();
        __builtin_amdgcn_s_setprio(1);
#pragma unroll
        for (int mi = 0; mi < 4; ++mi)
#pragma unroll
            for (int ni = 0; ni < 2; ++ni)
#pragma unroll
                for (int ks = 0; ks < 2; ++ks)
                    acc[mi][ni] = __builtin_amdgcn_mfma_f32_16x16x32_bf16(
                        Af[mi][ks], Bf[ni][ks], acc[mi][ni], 0, 0, 0);
        __builtin_amdgcn_s_setprio(0);
        WAITV2();
        SCB(); BARRIER(); SCB();

        // ===== phase 1: mi0-3 x ni2 (8 MFMA, Af reused); stage BE(t+1) ======
#pragma unroll
        for (int ks = 0; ks < 2; ++ks) Bf[2][ks] = rdB(bb, 2, ks);
        stageBE(tn, sb);
        SCB(); BARRIER(); LGKM0(); SCB();
        __builtin_amdgcn_s_setprio(1);
#pragma unroll
        for (int mi = 0; mi < 4; ++mi)
#pragma unroll
            for (int ks = 0; ks < 2; ++ks)
                acc[mi][2] = __builtin_amdgcn_mfma_f32_16x16x32_bf16(
                    Af[mi][ks], Bf[2][ks], acc[mi][2], 0, 0, 0);
        __builtin_amdgcn_s_setprio(0);
        SCB(); BARRIER(); SCB();          // no vmcnt here

        // ===== phase 2: mi4-7 x ni0-1 (16 MFMA, Bf reused); stage A1(t+1) ===
#pragma unroll
        for (int mi = 0; mi < 4; ++mi)
#pragma unroll
            for (int ks = 0; ks < 2; ++ks) Af[mi][ks] = rdA(ab, 4 + mi, ks);
        stageA(1, tn, sb);
        SCB(); BARRIER(); LGKM0(); SCB();
        __builtin_amdgcn_s_setprio(1);
#pragma unroll
        for (int mi = 0; mi < 4; ++mi)
#pragma unroll
            for (int ni = 0; ni < 2; ++ni)
#pragma unroll
                for (int ks = 0; ks < 2; ++ks)
                    acc[4 + mi][ni] = __builtin_amdgcn_mfma_f32_16x16x32_bf16(
                        Af[mi][ks], Bf[ni][ks], acc[4 + mi][ni], 0, 0, 0);
        __builtin_amdgcn_s_setprio(0);
        SCB(); BARRIER(); SCB();          // no vmcnt here

        // ===== phase 3: mi4-7 x ni2 (8 MFMA, all regs reused); stage BO =====
        stageBO(tn, sb);
        SCB(); BARRIER(); SCB();
        __builtin_amdgcn_s_setprio(1);
#pragma unroll
        for (int mi = 0; mi < 4; ++mi)
#pragma unroll
            for (int ks = 0; ks < 2; ++ks)
                acc[4 + mi][2] = __builtin_amdgcn_mfma_f32_16x16x32_bf16(
                    Af[mi][ks], Bf[2][ks], acc[4 + mi][2], 0, 0, 0);
        __builtin_amdgcn_s_setprio(0);
        WAITV3();
        SCB(); BARRIER(); SCB();
    }
    WAITV0();   // drain remaining/dummy loads: no LDS-DMA outlives the block

    // ---- epilogue: per 16-col group, Q|K (scaled bf16) or V (transposed) ----
    const float log2e8 = 0.125f * 1.44269504f;
#pragma unroll
    for (int mi = 0; mi < 8; ++mi) {
#pragma unroll
        for (int ni = 0; ni < 3; ++ni) {
            const int colg = n0 + wn * 48 + ni * 16 + l16;
            const float bb2 = bias[colg];
            if (colg >= 2 * CDIM) {
                // V: write transposed, 4 consecutive rows packed per 8B store
                const int row0 = m0 + wm * 128 + mi * 16 + quad * 4;
                short4v pk;
#pragma unroll
                for (int r = 0; r < 4; ++r) pk[r] = bf16_rn(acc[mi][ni][r] + bb2);
                *(short4v*)&Yv[(size_t)(colg - 2 * CDIM) * M_GEMM + row0] = pk;
            } else {
                // Q pre-scale folds 1/sqrt(64) and log2(e): attn does p = 2^s
                const float qs = (colg < CDIM) ? log2e8 : 1.0f;
#pragma unroll
                for (int r = 0; r < 4; ++r) {
                    const int row = m0 + wm * 128 + mi * 16 + quad * 4 + r;
                    Yqk[(size_t)row * QK_PITCH + colg] =
                        bf16_rn((acc[mi][ni][r] + bb2) * qs);
                }
            }
        }
    }
}

// ---------- Kernel 2: causal flash attention, R27 -----------------------------
// R27 = R22 tile body (swapped QK^T, in-register P, conflict-free hK) with
// CONCURRENT STRIP-PAIRING: one 8-wave/512-thread block runs strips bx
// (waves 0-3) and 31-bx (waves 4-7) over a SINGLE shared K/V stream,
// kt = 0..31-bx.  Why this beats both R22 and R23:
//  - R22's makespan defect (4 one-strip blocks/CU, lengths 1..32, no backfill
//    -> tail = one lone 4-wave block; occupancy 20.5%): here every CU hosts 2
//    identical-length blocks (ids i and i+256 share bx) -> tail has 8 waves
//    (two long strips in parallel), prefix has 16 waves/CU.
//  - R23's locality defect (sequential phases restarted kt -> FETCH doubled):
//    here kt advances from 0 in lockstep across all blocks (same as R22), and
//    K/V are staged ONCE per block for both strips -> per-(h,b) fetch drops
//    528 -> 392 tiles (-26%).
//  - staging halves per thread: 512 threads cover the 512 chunks of each
//    64x64 tile -> 1 K-issue + 1 V-issue per thread per tile.
// Short-strip waves skip compute via wave-uniform (kt <= qts) but still stage
// and hit every __syncthreads (all barriers unconditional).
__global__ __launch_bounds__(512) void attn_mfma(const short* __restrict__ qk,
                                                 const short* __restrict__ vT,
                                                 float* __restrict__ out) {
    const int b = blockIdx.z;
    const int h = blockIdx.y;
    const int bx = blockIdx.x;           // 0..15: strip pair (bx, 31-bx)
    const int tid = threadIdx.x;
    const int w = tid >> 6;              // wave 0..7
    const int ws = w >> 2;               // strip: 0 = bx (short), 1 = 31-bx
    const int wq = w & 3;                // quarter (16 q-rows) within strip
    const int lane = tid & 63;
    const int quad = lane >> 4;
    const int l16 = lane & 15;

    const int qts   = ws ? (31 - bx) : bx;   // this wave's strip q-tile
    const int ktmax = 31 - bx;               // long strip diagonal (>= qts)
    const int q0 = qts * 64;

    __shared__ short Ks[2][64 * 64];     // [buf][key][d], hK-swizzled   16 KB
    __shared__ short Vt[2][64 * 64];     // [buf][d][key], row&7-swizzled 16 KB

    // staging: chunk cid = tid (0..511) covers the whole 64x64 tile; ONE
    // K-issue + ONE V-issue per thread per tile.
    int koff, voff, ldso;
    {
        const int cid = tid;
        const int row = cid >> 3;
        const int hK = (row & 3) | (((row >> 3) & 1) << 2);   // conflict-free
        koff = row * QK_PITCH + (((cid & 7) ^ hK)) * 8;
        voff = row * M_GEMM + (((cid & 7) ^ (row & 7))) * 8;
        ldso = (w * 64) * 8;             // wave-uniform chunk base (shorts)
    }

    // Q fragments (B-layout for swapped QK^T: B[k=d][n=q], lane l16 = q)
    const short* qrow = qk + (size_t)(b * SEQ + q0 + wq * 16 + l16) * QK_PITCH + h * HDIM;
    short8 aq[2];
    aq[0] = *(const short8*)(qrow + quad * 8);
    aq[1] = *(const short8*)(qrow + 32 + quad * 8);

    float l_run = 0.f;                   // lane-scalar: q-row = l16
    f32x4 o_acc[4];
#pragma unroll
    for (int dt = 0; dt < 4; ++dt) o_acc[dt] = (f32x4){0.f, 0.f, 0.f, 0.f};

    const int qglob = q0 + wq * 16 + l16;    // this lane's q row (for mask)
    const short* kb0 = qk + (size_t)(b * SEQ) * QK_PITCH + CDIM + h * HDIM;
    const short* vb0 = vT + (size_t)(h * HDIM) * M_GEMM + b * SEQ;

    const int ksl = l16 & 7;

    // permuted K-row per nt-block: F(nt,l16) (quad-permuted base)
    const int Fq = ((l16 >> 2) << 3) + (l16 & 3);

    // prologue: stage tile 0 into buf 0
    gl2lds16(kb0 + koff, &Ks[0][ldso]);
    gl2lds16(vb0 + voff, &Vt[0][ldso]);
    __syncthreads();                     // prologue staging drained

    for (int kt = 0; kt <= ktmax; ++kt) {
        const int cur = kt & 1;

        // prefetch tile kt+1 into the other buffer (overlaps compute)
        if (kt < ktmax) {
            const short* kbase = kb0 + (size_t)(kt + 1) * 64 * QK_PITCH;
            const short* vbase = vb0 + (kt + 1) * 64;
            gl2lds16(kbase + koff, &Ks[cur ^ 1][ldso]);
            gl2lds16(vbase + voff, &Vt[cur ^ 1][ldso]);
        }

        if (kt <= qts) {                 // wave-uniform: short strip retires
            const short* KsC = Ks[cur];
            const short* VtC = Vt[cur];

            // ---- swapped QK^T: s[nt][r] = S[key][q=l16], key per-lane ------
            f32x4 s[4];
#pragma unroll
            for (int nt = 0; nt < 4; ++nt) s[nt] = (f32x4){0.f, 0.f, 0.f, 0.f};
            __builtin_amdgcn_s_setprio(1);
#pragma unroll
            for (int nt = 0; nt < 4; ++nt) {
                const int F  = (nt >> 1) * 32 + (nt & 1) * 4 + Fq;
                const int hF = (F & 3) | (((F >> 3) & 1) << 2);   // conflict-free
#pragma unroll
                for (int ks = 0; ks < 2; ++ks) {
                    short8 kf = *(const short8*)&KsC[F * 64 + (((ks * 4 + quad) ^ hF) * 8)];
                    s[nt] = __builtin_amdgcn_mfma_f32_16x16x32_bf16(kf, aq[ks], s[nt], 0, 0, 0);
                }
            }
            __builtin_amdgcn_s_setprio(0);

            // ---- softmax in registers: p = 2^s, pack into PV A-frags -------
            short8 pa0, pa1;
            float lsum = 0.f;
            if (kt < qts) {              // full tile
#pragma unroll
                for (int nt = 0; nt < 4; ++nt)
#pragma unroll
                    for (int r = 0; r < 4; ++r) {
                        float pp = __builtin_amdgcn_exp2f(s[nt][r]);
                        lsum += pp;
                        short pb = bf16_rn(pp);
                        if (nt < 2) pa0[(nt & 1) * 4 + r] = pb;
                        else        pa1[(nt & 1) * 4 + r] = pb;
                    }
            } else {                     // diagonal tile: causal mask
#pragma unroll
                for (int nt = 0; nt < 4; ++nt)
#pragma unroll
                    for (int r = 0; r < 4; ++r) {
                        int key = kt * 64 + (nt >> 1) * 32 + quad * 8 + (nt & 1) * 4 + r;
                        float pp = __builtin_amdgcn_exp2f(s[nt][r]);
                        pp = (key > qglob) ? 0.f : pp;
                        lsum += pp;
                        short pb = bf16_rn(pp);
                        if (nt < 2) pa0[(nt & 1) * 4 + r] = pb;
                        else        pa1[(nt & 1) * 4 + r] = pb;
                    }
            }
            l_run += lsum;

            // ---- PV: O[16 q][64 d] += P @ V; P is already the A-fragment ---
            __builtin_amdgcn_s_setprio(1);
#pragma unroll
            for (int dt = 0; dt < 4; ++dt)
#pragma unroll
                for (int ks = 0; ks < 2; ++ks) {
                    short8 bv = *(const short8*)&VtC[(dt * 16 + l16) * 64 +
                                                     ((ks * 4 + quad) ^ ksl) * 8];
                    o_acc[dt] = __builtin_amdgcn_mfma_f32_16x16x32_bf16(
                        ks ? pa1 : pa0, bv, o_acc[dt], 0, 0, 0);
                }
            __builtin_amdgcn_s_setprio(0);
        }

        // one barrier/tile: drains prefetch + guards buffer reuse (all waves)
        __syncthreads();
    }

    // ---- epilogue: l lives at q=l16 (partial over quads) -> reduce, redist -
    float l = l_run;
    l += __shfl_xor(l, 16);
    l += __shfl_xor(l, 32);              // now full row-sum for q=l16, all quads
#pragma unroll
    for (int r = 0; r < 4; ++r) {
        float lq = __shfl(l, quad * 4 + r);   // sum for q-row quad*4+r
        float inv = 1.f / lq;
        int row = q0 + wq * 16 + quad * 4 + r;
        float* optr = out + (size_t)(b * SEQ + row) * CDIM + h * HDIM;
#pragma unroll
        for (int dt = 0; dt < 4; ++dt)
            optr[dt * 16 + l16] = o_acc[dt][r] * inv;
    }
}

// ------------------------------- launch --------------------------------------
extern "C" void kernel_launch(void* const* d_in, const int* in_sizes, int n_in,
                              void* d_out, int out_size, void* d_ws, size_t ws_size,
                              hipStream_t stream) {
    const float* x      = (const float*)d_in[0];   // [B,T,C] fp32
    const float* w_attn = (const float*)d_in[1];   // [C,3C]  fp32
    const float* b_attn = (const float*)d_in[2];   // [3C]    fp32
    float* out = (float*)d_out;                    // [B,T,C] fp32

    // workspace: qk [4096][2048] 16.78MB | vT [1024][4096] 8.39MB | xb 8.39MB | wT 6.29MB
    short* qk  = (short*)d_ws;
    short* vT  = (short*)((char*)d_ws + 16777216);
    short* xb  = (short*)((char*)d_ws + 25165824);
    short* wT  = (short*)((char*)d_ws + 33554432);

    cvt_fused<<<2048 + 768, 256, 0, stream>>>(x, w_attn, xb, wT);

    dim3 g1(N_GEMM / 192, M_GEMM / 256);                                // (16,16)
    qkv_gemm_8ph<<<g1, 512, 0, stream>>>(xb, wT, b_attn, qk, vT);

    dim3 g2(SEQ / 128, NHEAD, BSZ);                                     // (16,16,2)
    attn_mfma<<<g2, 512, 0, stream>>>(qk, vT, out);
}